// Round 10
// baseline (131.641 us; speedup 1.0000x reference)
//
#include <hip/hip_runtime.h>
#include <stdint.h>

typedef unsigned char      u8;
typedef unsigned int       u32;

#define N_ROWS 8192
#define N_HALF 4096
#define DDIM   1024
#define TILE   128
#define NKT    8              // k-chunks of 128
#define NBLK_PREP 1024
#define NTILES (64 * 65 / 2)  // 2080 triangular 128x128 tiles
#define NXCD   8
#define TPX    (NTILES / NXCD)  // 260, exact -> bijective chunk swizzle
#define NSUMS  (NTILES * 2)     // per-wave partials (2 waves/block)

typedef int   i32x4 __attribute__((ext_vector_type(4)));
typedef int   i32x8 __attribute__((ext_vector_type(8)));
typedef float f32x4 __attribute__((ext_vector_type(4)));

// ---- workspace (~8.05 MB): every byte written before read; zero atomics ----
// xb layout (FRAGMENT-MAJOR, R8-validated): for row-group rg = r>>4 and
// k-chunk kc = k>>7, a 2 KB block at (rg*8 + kc)*2048 stores bytes such that
// MFMA lane l reads its 32-byte fragment slice as TWO DENSE dwordx4:
//   block[h*1024 + l*16 + j] = X8[rg*16 + (l&15)][kc*128 + (l>>4)*32 + h*16 + j]
#define OFF_X8   ((size_t)0)
#define SZ_X8    ((size_t)N_ROWS * DDIM)          // 8 MB fp8 fragment-major
#define OFF_SQ   (SZ_X8)                          // 8192 f32 row sq-norms (fp8-consistent)
#define OFF_SQP  (OFF_SQ + (size_t)N_ROWS * 4)    // sqpart[1024]
#define OFF_TS   (OFF_SQP + (size_t)NBLK_PREP * 4)// tilesum[4160] per-wave partials
#define WS_NEED  (OFF_TS + (size_t)NSUMS * 4)

// ---------------------------------------------------------------------------
// Kernel A: fp32 -> fp8(e4m3, RNE HW cvt), row sq-norms from DEQUANTIZED fp8
// (keeps diagonal L2 ~ 0), per-block sum-of-sq partial. R8-validated
// fragment-major writer, untouched.
// ---------------------------------------------------------------------------
__global__ __launch_bounds__(256) void prep_kernel(const float* __restrict__ src,
                                                   const float* __restrict__ tgt,
                                                   u32* __restrict__ xb,
                                                   float* __restrict__ sqv,
                                                   float* __restrict__ sqpart) {
  __shared__ float wsq[4];
  const int tid  = threadIdx.x;
  const int lane = tid & 63;
  const int wave = tid >> 6;
  const int gw   = blockIdx.x * 4 + wave;     // 0..4095
  float wsum = 0.f;                           // valid on lane 0
#pragma unroll
  for (int rr = 0; rr < 2; ++rr) {
    const int r = gw * 2 + rr;                // 0..8191
    const float* rowp = (r < N_HALF) ? (src + (size_t)r * DDIM)
                                     : (tgt + (size_t)(r - N_HALF) * DDIM);
    const int rg  = r >> 4;
    const int r16 = r & 15;
    float s = 0.f;
#pragma unroll
    for (int chn = 0; chn < 4; ++chn) {
      const int k0 = chn * 256 + lane * 4;    // 4 consecutive k
      float4 v = *(const float4*)(rowp + k0);
      int p = __builtin_amdgcn_cvt_pk_fp8_f32(v.x, v.y, 0, false);
      p     = __builtin_amdgcn_cvt_pk_fp8_f32(v.z, v.w, p, true);
      // fragment-major index (u32 units): block (rg*8+kc) of 512 u32;
      // within: h*256 + l'*4 + (k0&15)/4, l' = r16 + 16*((k0&127)>>5)
      const int kc = k0 >> 7;
      const int kk = k0 & 127;
      const int lp = r16 + ((kk >> 5) << 4);
      const int h  = (kk >> 4) & 1;
      xb[(size_t)(rg * 8 + kc) * 512 + h * 256 + lp * 4 + ((k0 & 15) >> 2)] = (u32)p;
      float fx = __builtin_amdgcn_cvt_f32_fp8(p, 0);
      float fy = __builtin_amdgcn_cvt_f32_fp8(p, 1);
      float fz = __builtin_amdgcn_cvt_f32_fp8(p, 2);
      float fw = __builtin_amdgcn_cvt_f32_fp8(p, 3);
      s = fmaf(fx, fx, s); s = fmaf(fy, fy, s);
      s = fmaf(fz, fz, s); s = fmaf(fw, fw, s);
    }
#pragma unroll
    for (int off = 32; off; off >>= 1) s += __shfl_down(s, off);
    if (lane == 0) { sqv[r] = s; wsum += s; }
  }
  if (lane == 0) wsq[wave] = wsum;
  __syncthreads();
  if (tid == 0) sqpart[blockIdx.x] = (wsq[0] + wsq[1]) + (wsq[2] + wsq[3]);
}

// ---------------------------------------------------------------------------
// Kernel B: fused Gram + MMD, MX-fp8. R10: FAT-WAVE zero-LDS streaming.
// Ten-round model: the L2->CU fill path sustains ~32 B/cy/CU (19.7 TB/s) for
// independent vector loads; DMA port is slower (16 B/cy) and does NOT add
// (R9: split-path 13.5 TB/s combined < R8's vector-only). R8 sat exactly at
// the port: 1.065 GB / 19.7 TB/s = 54 us. Lever: bytes/output. Wave tile
// 64x128 costs (4+8)*2KB per kt for 8192 outputs = 2.93 B/elem vs 64x64's
// 4 B/elem -> 798 MB total -> ~40 us at the same port rate.
// Structure: 2080 triangular 128x128 tiles, 2 waves/block (row halves);
// ZERO barriers (bwsh per-wave redundant in regs; per-wave tilesum entry).
// Both waves read identical B fragments near-lockstep -> 2nd wave's B reads
// largely L1-hit (16KB/kt < 32KB L1) - possible upside past the port rate.
// VGPR budget: acc[4][8]=128 + af 32 + bf <=64 + addr ~= 230 < 256 ->
// __launch_bounds__(128,2), 8 waves/CU; MLP 24 loads/wave in flight covers
// BW*latency (~13 loads). Fragment maps R8-verbatim.
// MFMA: mfma_scale_f32_16x16x128_f8f6f4, unit E8M0 scales (exact fp8 GEMM).
// C/D: col = lane&15, row = q*4 + v. Math identical to R8 -> same absmax.
// ---------------------------------------------------------------------------
__global__ __launch_bounds__(128, 2) void mmd_kernel(const u8* __restrict__ xb,
                                                     const float* __restrict__ sqv,
                                                     const float* __restrict__ sqpart,
                                                     float* __restrict__ tilesum) {
  // XCD-chunked swizzle (R8-validated): XCD (t0&7) gets [x*260,(x+1)*260)
  const int t0 = (int)blockIdx.x;
  const int t  = (t0 & 7) * TPX + (t0 >> 3);

  // triangular decode: tile t -> (by, bx) with by >= bx
  int by = (int)((sqrtf(8.f * (float)t + 1.f) - 1.f) * 0.5f);
  while ((by + 1) * (by + 2) / 2 <= t) ++by;
  while (by * (by + 1) / 2 > t) --by;
  const int bx = t - by * (by + 1) / 2;

  const int tid  = threadIdx.x;
  const int lane = tid & 63;
  const int wave = tid >> 6;         // 0..1 (row half)
  const int m16  = lane & 15;        // MFMA m/n index
  const int q    = lane >> 4;        // quad: k-block owner
  const int wrow = wave * 64;
  const int rowbase = by * TILE;
  const int colbase = bx * TILE;

  // ---- bandwidth const: per-wave redundant, in registers (no barrier) ----
  float S = 0.f;
#pragma unroll
  for (int i = 0; i < 16; ++i) S += sqpart[lane * 16 + i];
#pragma unroll
  for (int off = 32; off; off >>= 1) S += __shfl_down(S, off);
  S = __shfl(S, 0);
  const double sumL2 = 2.0 * 8192.0 * (double)S;   // ||colsum||^2 term ~1e-4 rel, dropped
  const double bwv   = sumL2 / (8192.0 * 8192.0 - 8192.0) / 4.0;
  const float  nib   = (float)(-0.0625 * 1.4426950408889634 / bwv);  // -(1/16)/bw * log2e

  f32x4 acc[4][8];
#pragma unroll
  for (int mi = 0; mi < 4; ++mi)
#pragma unroll
    for (int ni = 0; ni < 8; ++ni) acc[mi][ni] = f32x4{0.f, 0.f, 0.f, 0.f};

  // fragment bases (R8-verbatim maps): rg runs of 8 k-chunks of 2 KB
  const u8* pA0 = xb + (size_t)(((rowbase + wrow) >> 4) * 8) * 2048 + lane * 16;
  const u8* pB0 = xb + (size_t)((colbase >> 4) * 8) * 2048 + lane * 16;

#pragma unroll 1
  for (int kt = 0; kt < NKT; ++kt) {
    const u8* pA = pA0 + kt * 2048;
    const u8* pB = pB0 + kt * 2048;
    i32x8 af[4];
#pragma unroll
    for (int mi = 0; mi < 4; ++mi) {
      i32x4 lo = *(const i32x4*)(pA + mi * 16384);
      i32x4 hi = *(const i32x4*)(pA + mi * 16384 + 1024);
      af[mi] = __builtin_shufflevector(lo, hi, 0, 1, 2, 3, 4, 5, 6, 7);
    }
#pragma unroll
    for (int ni = 0; ni < 8; ++ni) {
      i32x4 lo = *(const i32x4*)(pB + ni * 16384);
      i32x4 hi = *(const i32x4*)(pB + ni * 16384 + 1024);
      i32x8 bfv = __builtin_shufflevector(lo, hi, 0, 1, 2, 3, 4, 5, 6, 7);
#pragma unroll
      for (int mi = 0; mi < 4; ++mi)
        acc[mi][ni] = __builtin_amdgcn_mfma_scale_f32_16x16x128_f8f6f4(
            af[mi], bfv, acc[mi][ni],
            0, 0,                     // cbsz=fp8(e4m3), blgp=fp8(e4m3)
            0, 0x7F7F7F7F,            // opsel_a, scale_a = E8M0 unit (2^0)
            0, 0x7F7F7F7F);           // opsel_b, scale_b
    }
  }

  // ---- fused epilogue (C/D: col = lane&15, row = q*4 + v) ----
  float sqc[8];
#pragma unroll
  for (int ni = 0; ni < 8; ++ni) sqc[ni] = sqv[colbase + ni * 16 + m16];

  float tsum = 0.f;
#pragma unroll
  for (int mi = 0; mi < 4; ++mi) {
#pragma unroll
    for (int v = 0; v < 4; ++v) {
      const float sqr = sqv[rowbase + wrow + mi * 16 + q * 4 + v];
#pragma unroll
      for (int ni = 0; ni < 8; ++ni) {
        const float L2 = fmaf(-2.f, acc[mi][ni][v], sqr + sqc[ni]);
        const float e16 = exp2f(L2 * nib);      // log2e pre-folded into nib
        const float e8 = e16 * e16;
        const float e4 = e8 * e8;
        const float e2 = e4 * e4;
        const float e1 = e2 * e2;
        tsum += (e16 + e8) + (e4 + e2) + e1;
      }
    }
  }
#pragma unroll
  for (int off = 32; off; off >>= 1) tsum += __shfl_down(tsum, off);
  // per-wave partial (no cross-wave reduce -> no barrier); fixed slot ->
  // deterministic final sum in fin.
  if (lane == 0) {
    const float sgn = ((by < 32) == (bx < 32)) ? 1.f : -1.f;
    const float wgt = (bx == by) ? 1.f : 2.f;
    tilesum[t0 * 2 + wave] = sgn * wgt * tsum;
  }
}

// ---------------------------------------------------------------------------
// Kernel C: deterministic final reduce (fixed order, double) -> mean / n^2.
// Separate dispatch (R4-validated: no cross-block ticket).
// ---------------------------------------------------------------------------
__global__ void fin_kernel(const float* __restrict__ tilesum, float* __restrict__ out) {
  __shared__ double red[4];
  const int t = threadIdx.x, lane = t & 63, wave = t >> 6;
  double s = 0.0;
  for (int i = t; i < NSUMS; i += 256) s += (double)tilesum[i];
#pragma unroll
  for (int off = 32; off; off >>= 1) s += __shfl_down(s, off);
  if (lane == 0) red[wave] = s;
  __syncthreads();
  if (t == 0) {
    double total = red[0] + red[1] + red[2] + red[3];
    out[0] = (float)(total / 16777216.0);   // mean over n^2 = 4096^2
  }
}

extern "C" void kernel_launch(void* const* d_in, const int* in_sizes, int n_in,
                              void* d_out, int out_size, void* d_ws, size_t ws_size,
                              hipStream_t stream) {
  if (ws_size < WS_NEED) return;  // ~8.05 MB scratch
  const float* src = (const float*)d_in[0];
  const float* tgt = (const float*)d_in[1];
  char* ws = (char*)d_ws;
  u32*   xb  = (u32*)(ws + OFF_X8);
  float* sqv = (float*)(ws + OFF_SQ);
  float* sqp = (float*)(ws + OFF_SQP);
  float* ts  = (float*)(ws + OFF_TS);

  prep_kernel<<<NBLK_PREP, 256, 0, stream>>>(src, tgt, xb, sqv, sqp);
  mmd_kernel<<<NTILES, 128, 0, stream>>>((const u8*)xb, sqv, sqp, ts);
  fin_kernel<<<1, 256, 0, stream>>>(ts, (float*)d_out);
}

// Round 11
// 124.085 us; speedup vs baseline: 1.0609x; 1.0609x over previous
//
#include <hip/hip_runtime.h>
#include <stdint.h>

typedef unsigned char      u8;
typedef unsigned int       u32;

#define N_ROWS 8192
#define N_HALF 4096
#define DDIM   1024
#define TILE   128
#define NKT    8              // k-chunks of 128
#define NBLK_PREP 1024
#define NTILES (64 * 65 / 2)  // 2080 triangular 128x128 tiles
#define NXCD   8
#define TPX    (NTILES / NXCD)  // 260, exact -> bijective chunk swizzle

typedef int   i32x4 __attribute__((ext_vector_type(4)));
typedef int   i32x8 __attribute__((ext_vector_type(8)));
typedef float f32x4 __attribute__((ext_vector_type(4)));

// ---- workspace (~8.04 MB): every byte written before read; zero atomics ----
// xb layout (FRAGMENT-MAJOR, R8-validated): for row-group rg = r>>4 and
// k-chunk kc = k>>7, a 2 KB block at (rg*8 + kc)*2048 stores bytes such that
// MFMA lane l reads its 32-byte fragment slice as TWO DENSE dwordx4:
//   block[h*1024 + l*16 + j] = X8[rg*16 + (l&15)][kc*128 + (l>>4)*32 + h*16 + j]
#define OFF_X8   ((size_t)0)
#define SZ_X8    ((size_t)N_ROWS * DDIM)          // 8 MB fp8 fragment-major
#define OFF_SQ   (SZ_X8)                          // 8192 f32 row sq-norms (fp8-consistent)
#define OFF_SQP  (OFF_SQ + (size_t)N_ROWS * 4)    // sqpart[1024]
#define OFF_TS   (OFF_SQP + (size_t)NBLK_PREP * 4)// tilesum[2080]
#define WS_NEED  (OFF_TS + (size_t)NTILES * 4)

// ---------------------------------------------------------------------------
// Kernel A: fp32 -> fp8(e4m3, RNE HW cvt), row sq-norms from DEQUANTIZED fp8
// (keeps diagonal L2 ~ 0), per-block sum-of-sq partial. R8-validated
// fragment-major writer, untouched.
// ---------------------------------------------------------------------------
__global__ __launch_bounds__(256) void prep_kernel(const float* __restrict__ src,
                                                   const float* __restrict__ tgt,
                                                   u32* __restrict__ xb,
                                                   float* __restrict__ sqv,
                                                   float* __restrict__ sqpart) {
  __shared__ float wsq[4];
  const int tid  = threadIdx.x;
  const int lane = tid & 63;
  const int wave = tid >> 6;
  const int gw   = blockIdx.x * 4 + wave;     // 0..4095
  float wsum = 0.f;                           // valid on lane 0
#pragma unroll
  for (int rr = 0; rr < 2; ++rr) {
    const int r = gw * 2 + rr;                // 0..8191
    const float* rowp = (r < N_HALF) ? (src + (size_t)r * DDIM)
                                     : (tgt + (size_t)(r - N_HALF) * DDIM);
    const int rg  = r >> 4;
    const int r16 = r & 15;
    float s = 0.f;
#pragma unroll
    for (int chn = 0; chn < 4; ++chn) {
      const int k0 = chn * 256 + lane * 4;    // 4 consecutive k
      float4 v = *(const float4*)(rowp + k0);
      int p = __builtin_amdgcn_cvt_pk_fp8_f32(v.x, v.y, 0, false);
      p     = __builtin_amdgcn_cvt_pk_fp8_f32(v.z, v.w, p, true);
      // fragment-major index (u32 units): block (rg*8+kc) of 512 u32;
      // within: h*256 + l'*4 + (k0&15)/4, l' = r16 + 16*((k0&127)>>5)
      const int kc = k0 >> 7;
      const int kk = k0 & 127;
      const int lp = r16 + ((kk >> 5) << 4);
      const int h  = (kk >> 4) & 1;
      xb[(size_t)(rg * 8 + kc) * 512 + h * 256 + lp * 4 + ((k0 & 15) >> 2)] = (u32)p;
      float fx = __builtin_amdgcn_cvt_f32_fp8(p, 0);
      float fy = __builtin_amdgcn_cvt_f32_fp8(p, 1);
      float fz = __builtin_amdgcn_cvt_f32_fp8(p, 2);
      float fw = __builtin_amdgcn_cvt_f32_fp8(p, 3);
      s = fmaf(fx, fx, s); s = fmaf(fy, fy, s);
      s = fmaf(fz, fz, s); s = fmaf(fw, fw, s);
    }
#pragma unroll
    for (int off = 32; off; off >>= 1) s += __shfl_down(s, off);
    if (lane == 0) { sqv[r] = s; wsum += s; }
  }
  if (lane == 0) wsq[wave] = wsum;
  __syncthreads();
  if (tid == 0) sqpart[blockIdx.x] = (wsq[0] + wsq[1]) + (wsq[2] + wsq[3]);
}

// ---------------------------------------------------------------------------
// Kernel B: fused Gram + MMD, MX-fp8. R11 = R8 VERBATIM + two single-variable
// levers on the concurrency*latency wall (11-round model: rate = outstanding
// bytes / latency; R8 = 12 waves x 16 loads x 16B = 3KB @ ~95cy = 32 B/cy):
//  (1) __launch_bounds__(256,4): R8 sits at exactly 64 VGPR + 64 AGPR =
//      128/wave = the 16-wave/CU boundary; (256,3) targeted only 3 blocks/CU.
//      4th resident block = +33% outstanding bytes. No spill expected (usage
//      already meets the 128 cap).
//  (2) bare s_barrier at each kt top: NO correctness role (no shared data in
//      the K-loop) - pure lockstep hint so the 2 waves reading each fragment
//      (A: wave-pairs (0,1),(2,3); B: (0,2),(1,3)) issue in the same window
//      and the second reader hits L1 (~60cy) instead of L2 (~200cy).
//      Resident blocks also share A panels (XCD-chunk -> same by, adjacent
//      bx). Removable single-variable if it regresses.
// Everything else (fragment maps, decode, epilogue, swizzle) R8-verbatim.
// MFMA: mfma_scale_f32_16x16x128_f8f6f4, unit E8M0 scales (exact fp8 GEMM).
// C/D: col = lane&15, row = q*4 + v. Math identical to R8 -> same absmax.
// ---------------------------------------------------------------------------
__global__ __launch_bounds__(256, 4) void mmd_kernel(const u8* __restrict__ xb,
                                                     const float* __restrict__ sqv,
                                                     const float* __restrict__ sqpart,
                                                     float* __restrict__ tilesum) {
  __shared__ float wred[4];
  __shared__ float bwsh;

  // XCD-chunked swizzle (R8-validated): XCD (t0&7) gets [x*260,(x+1)*260)
  const int t0 = (int)blockIdx.x;
  const int t  = (t0 & 7) * TPX + (t0 >> 3);

  // triangular decode: tile t -> (by, bx) with by >= bx
  int by = (int)((sqrtf(8.f * (float)t + 1.f) - 1.f) * 0.5f);
  while ((by + 1) * (by + 2) / 2 <= t) ++by;
  while (by * (by + 1) / 2 > t) --by;
  const int bx = t - by * (by + 1) / 2;

  const int tid  = threadIdx.x;
  const int lane = tid & 63;
  const int wave = tid >> 6;
  const int m16  = lane & 15;        // MFMA m/n index
  const int q    = lane >> 4;        // quad: k-block owner
  const int wrow = (wave >> 1) * 64; // wave's 64x64 quadrant
  const int wcol = (wave & 1) * 64;
  const int rowbase = by * TILE;
  const int colbase = bx * TILE;

  // ---- bandwidth from sqpart (wave 0; consumed after the final barrier) ----
  if (tid < 64) {
    float S = 0.f;
#pragma unroll
    for (int i = 0; i < 16; ++i) S += sqpart[tid * 16 + i];
#pragma unroll
    for (int off = 32; off; off >>= 1) S += __shfl_down(S, off);
    if (tid == 0) {
      double sumL2 = 2.0 * 8192.0 * (double)S;   // ||colsum||^2 term ~1e-4 rel, dropped
      double bwv = sumL2 / (8192.0 * 8192.0 - 8192.0) / 4.0;
      bwsh = (float)(-0.0625 * 1.4426950408889634 / bwv);  // -(1/16)/bw * log2e
    }
  }

  f32x4 acc[4][4];
#pragma unroll
  for (int mi = 0; mi < 4; ++mi)
#pragma unroll
    for (int ni = 0; ni < 4; ++ni) acc[mi][ni] = f32x4{0.f, 0.f, 0.f, 0.f};

  // fragment bases (R8-verbatim): rg runs of 8 k-chunks of 2 KB; +16384/rg
  const u8* pA0 = xb + (size_t)(((rowbase + wrow) >> 4) * 8) * 2048 + lane * 16;
  const u8* pB0 = xb + (size_t)(((colbase + wcol) >> 4) * 8) * 2048 + lane * 16;

#pragma unroll 1
  for (int kt = 0; kt < NKT; ++kt) {
    // lockstep hint: align the 4 waves' load windows (see header). No data
    // dependency crosses this barrier; uniform count across all waves.
    asm volatile("s_barrier" ::: "memory");
    const u8* pA = pA0 + kt * 2048;
    const u8* pB = pB0 + kt * 2048;
    i32x8 af[4], bf[4];
#pragma unroll
    for (int mi = 0; mi < 4; ++mi) {
      i32x4 lo = *(const i32x4*)(pA + mi * 16384);
      i32x4 hi = *(const i32x4*)(pA + mi * 16384 + 1024);
      af[mi] = __builtin_shufflevector(lo, hi, 0, 1, 2, 3, 4, 5, 6, 7);
    }
#pragma unroll
    for (int ni = 0; ni < 4; ++ni) {
      i32x4 lo = *(const i32x4*)(pB + ni * 16384);
      i32x4 hi = *(const i32x4*)(pB + ni * 16384 + 1024);
      bf[ni] = __builtin_shufflevector(lo, hi, 0, 1, 2, 3, 4, 5, 6, 7);
    }
#pragma unroll
    for (int mi = 0; mi < 4; ++mi)
#pragma unroll
      for (int ni = 0; ni < 4; ++ni)
        acc[mi][ni] = __builtin_amdgcn_mfma_scale_f32_16x16x128_f8f6f4(
            af[mi], bf[ni], acc[mi][ni],
            0, 0,                     // cbsz=fp8(e4m3), blgp=fp8(e4m3)
            0, 0x7F7F7F7F,            // opsel_a, scale_a = E8M0 unit (2^0)
            0, 0x7F7F7F7F);           // opsel_b, scale_b
  }

  __syncthreads();                   // publish bwsh (only full barrier)

  // ---- fused epilogue (C/D: col = lane&15, row = q*4 + v) ----
  const float nib = bwsh;
  float sqc[4];
#pragma unroll
  for (int ni = 0; ni < 4; ++ni) sqc[ni] = sqv[colbase + wcol + ni * 16 + m16];

  float tsum = 0.f;
#pragma unroll
  for (int mi = 0; mi < 4; ++mi) {
#pragma unroll
    for (int v = 0; v < 4; ++v) {
      const float sqr = sqv[rowbase + wrow + mi * 16 + q * 4 + v];
#pragma unroll
      for (int ni = 0; ni < 4; ++ni) {
        const float L2 = fmaf(-2.f, acc[mi][ni][v], sqr + sqc[ni]);
        const float e16 = exp2f(L2 * nib);      // log2e pre-folded into nib
        const float e8 = e16 * e16;
        const float e4 = e8 * e8;
        const float e2 = e4 * e4;
        const float e1 = e2 * e2;
        tsum += (e16 + e8) + (e4 + e2) + e1;
      }
    }
  }
#pragma unroll
  for (int off = 32; off; off >>= 1) tsum += __shfl_down(tsum, off);
  if (lane == 0) wred[wave] = tsum;
  __syncthreads();
  if (tid == 0) {
    const float bs = (wred[0] + wred[1]) + (wred[2] + wred[3]);
    const float sgn = ((by < 32) == (bx < 32)) ? 1.f : -1.f;
    const float wgt = (bx == by) ? 1.f : 2.f;
    tilesum[t] = sgn * wgt * bs;
  }
}

// ---------------------------------------------------------------------------
// Kernel C: deterministic final reduce (fixed order, double) -> mean / n^2.
// Separate dispatch (R4-validated: no cross-block ticket).
// ---------------------------------------------------------------------------
__global__ void fin_kernel(const float* __restrict__ tilesum, float* __restrict__ out) {
  __shared__ double red[4];
  const int t = threadIdx.x, lane = t & 63, wave = t >> 6;
  double s = 0.0;
  for (int i = t; i < NTILES; i += 256) s += (double)tilesum[i];
#pragma unroll
  for (int off = 32; off; off >>= 1) s += __shfl_down(s, off);
  if (lane == 0) red[wave] = s;
  __syncthreads();
  if (t == 0) {
    double total = red[0] + red[1] + red[2] + red[3];
    out[0] = (float)(total / 16777216.0);   // mean over n^2 = 4096^2
  }
}

extern "C" void kernel_launch(void* const* d_in, const int* in_sizes, int n_in,
                              void* d_out, int out_size, void* d_ws, size_t ws_size,
                              hipStream_t stream) {
  if (ws_size < WS_NEED) return;  // ~8.04 MB scratch
  const float* src = (const float*)d_in[0];
  const float* tgt = (const float*)d_in[1];
  char* ws = (char*)d_ws;
  u32*   xb  = (u32*)(ws + OFF_X8);
  float* sqv = (float*)(ws + OFF_SQ);
  float* sqp = (float*)(ws + OFF_SQP);
  float* ts  = (float*)(ws + OFF_TS);

  prep_kernel<<<NBLK_PREP, 256, 0, stream>>>(src, tgt, xb, sqv, sqp);
  mmd_kernel<<<NTILES, 256, 0, stream>>>((const u8*)xb, sqv, sqp, ts);
  fin_kernel<<<1, 256, 0, stream>>>(ts, (float*)d_out);
}